// Round 1
// baseline (1039.016 us; speedup 1.0000x reference)
//
#include <hip/hip_runtime.h>

#define MDIM 4096
#define KDIM 4096
#define NDIM 14336

typedef __attribute__((ext_vector_type(8))) short bf16x8;
typedef __attribute__((ext_vector_type(4))) short bf16x4;
typedef __attribute__((ext_vector_type(4))) float f32x4;

// round-to-nearest-even fp32 -> bf16
__device__ __forceinline__ unsigned short f2bf(float f) {
  unsigned u = __float_as_uint(f);
  return (unsigned short)((u + 0x7FFFu + ((u >> 16) & 1u)) >> 16);
}

// async 16B global -> LDS (lane i lands at ldsbase + i*16)
__device__ __forceinline__ void async_copy16(const void* g, void* l) {
  __builtin_amdgcn_global_load_lds((const __attribute__((address_space(1))) unsigned*)g,
                                   (__attribute__((address_space(3))) unsigned*)l, 16, 0, 0);
}

// ---------------- P1: X fp32 -> bf16 ----------------
__global__ __launch_bounds__(256) void cvt_x_kernel(const float* __restrict__ X,
                                                    short* __restrict__ Xb) {
  const int i = blockIdx.x * 256 + threadIdx.x;  // 8 floats per thread
  const float4* p = (const float4*)X + (size_t)i * 2;
  const float4 a = p[0], b = p[1];
  bf16x8 v;
  v[0] = f2bf(a.x); v[1] = f2bf(a.y); v[2] = f2bf(a.z); v[3] = f2bf(a.w);
  v[4] = f2bf(b.x); v[5] = f2bf(b.y); v[6] = f2bf(b.z); v[7] = f2bf(b.w);
  *((bf16x8*)Xb + i) = v;
}

// ---------------- P2: dequant Q[K][N] int32 -> Wt[N][K] bf16 (transposed) ----------------
// Register-transposed 4x4 blocks: 4 int4 loads + 4 ds_write_b64 + 4 ds_read_b64 per thread.
constexpr int TPD = 76;  // shorts; 152 B row stride: b64-aligned, non-pow2 banks
__global__ __launch_bounds__(256) void dequant_w_kernel(const int* __restrict__ Q,
                                                        const float* __restrict__ S,
                                                        short* __restrict__ Wt) {
  __shared__ short Ls[64 * TPD];  // [n][k]
  const int k0 = blockIdx.x * 64;
  const int n0 = blockIdx.y * 64;
  const int t  = threadIdx.x;
  const int g  = k0 >> 6;  // GROUP == 64

  // phase 1: 4x4 block at (k0+rb, n0+n4): coalesced int4 row reads
  const int n4 = (t & 15) * 4;
  const int rb = (t >> 4) * 4;
  const float4 s4 = *(const float4*)(S + (size_t)g * NDIM + n0 + n4);
  int4 q[4];
#pragma unroll
  for (int i = 0; i < 4; ++i)
    q[i] = *(const int4*)(Q + (size_t)(k0 + rb + i) * NDIM + n0 + n4);
  // transpose in registers: column j -> 4 consecutive k
  {
    bf16x4 v;
    v[0] = (short)f2bf((float)(q[0].x - 8) * s4.x);
    v[1] = (short)f2bf((float)(q[1].x - 8) * s4.x);
    v[2] = (short)f2bf((float)(q[2].x - 8) * s4.x);
    v[3] = (short)f2bf((float)(q[3].x - 8) * s4.x);
    *(bf16x4*)&Ls[(n4 + 0) * TPD + rb] = v;
    v[0] = (short)f2bf((float)(q[0].y - 8) * s4.y);
    v[1] = (short)f2bf((float)(q[1].y - 8) * s4.y);
    v[2] = (short)f2bf((float)(q[2].y - 8) * s4.y);
    v[3] = (short)f2bf((float)(q[3].y - 8) * s4.y);
    *(bf16x4*)&Ls[(n4 + 1) * TPD + rb] = v;
    v[0] = (short)f2bf((float)(q[0].z - 8) * s4.z);
    v[1] = (short)f2bf((float)(q[1].z - 8) * s4.z);
    v[2] = (short)f2bf((float)(q[2].z - 8) * s4.z);
    v[3] = (short)f2bf((float)(q[3].z - 8) * s4.z);
    *(bf16x4*)&Ls[(n4 + 2) * TPD + rb] = v;
    v[0] = (short)f2bf((float)(q[0].w - 8) * s4.w);
    v[1] = (short)f2bf((float)(q[1].w - 8) * s4.w);
    v[2] = (short)f2bf((float)(q[2].w - 8) * s4.w);
    v[3] = (short)f2bf((float)(q[3].w - 8) * s4.w);
    *(bf16x4*)&Ls[(n4 + 3) * TPD + rb] = v;
  }
  __syncthreads();

  // phase 2: row nr, 16 shorts starting kc; 4 lanes cover one 128 B row segment
  const int nr = t >> 2;
  const int kc = (t & 3) * 16;
  const short* lr = &Ls[nr * TPD + kc];
  bf16x4 a0 = *(const bf16x4*)(lr + 0);
  bf16x4 a1 = *(const bf16x4*)(lr + 4);
  bf16x4 a2 = *(const bf16x4*)(lr + 8);
  bf16x4 a3 = *(const bf16x4*)(lr + 12);
  bf16x8 v0, v1;
#pragma unroll
  for (int j = 0; j < 4; ++j) { v0[j] = a0[j]; v0[4 + j] = a1[j]; v1[j] = a2[j]; v1[4 + j] = a3[j]; }
  short* wp = Wt + (size_t)(n0 + nr) * KDIM + k0 + kc;
  *(bf16x8*)wp = v0;
  *(bf16x8*)(wp + 8) = v1;
}

// ---------------- GEMM v2: Xb[M][K] x Wt[N][K] -> Out[M][N] ----------------
// 256x128 tile, BK=64, 8 waves (4M x 2N, 64x64 each), double-buffered LDS,
// prefetch issued BEFORE compute so the single per-tile __syncthreads vmcnt(0)
// drain lands after a full compute window (T3 minimum-2-phase). XOR-swizzled
// LDS slots (slot s of row r holds k-chunk s^(r&7)) kept from verified v1.
// XCD-aware bijective block swizzle (1792 blocks = 8 x 224).
__global__ __launch_bounds__(512, 1)
void gemm_bf16tt(const short* __restrict__ Xb, const short* __restrict__ Wt,
                 float* __restrict__ Out) {
  __shared__ short As[2][256 * 64];  // 64 KiB
  __shared__ short Bs[2][128 * 64];  // 32 KiB

  // XCD swizzle: consecutive-on-one-XCD chunks of 224 blocks (14 n-panels)
  const int lin = blockIdx.y * gridDim.x + blockIdx.x;   // dispatch order, x fastest
  const int swz = (lin & 7) * 224 + (lin >> 3);          // bijective: 1792 % 8 == 0
  const int bm = (swz & 15) * 256;
  const int bn = (swz >> 4) * 128;

  const int tid = threadIdx.x, lane = tid & 63, wave = tid >> 6;
  const int wm = (wave >> 1) * 64;  // 4 waves along M
  const int wn = (wave & 1) * 64;   // 2 waves along N
  const int quad = lane >> 4, l16 = lane & 15;
  const int lx = l16 & 7;

  f32x4 acc[4][4];
#pragma unroll
  for (int i = 0; i < 4; ++i)
#pragma unroll
    for (int j = 0; j < 4; ++j) acc[i][j] = (f32x4){0.f, 0.f, 0.f, 0.f};

  // staging: 512 threads cover 64 rows per call (row = p*64 + tid>>3, slot tid&7)
  // global k-chunk pre-swizzled: kof = ((tid&7) ^ (row&7)) * 8
  const int row0 = tid >> 3;                       // 0..63
  const int kof  = ((tid & 7) ^ (row0 & 7)) * 8;   // p*64 keeps row&7 invariant
  const size_t aoff = (size_t)(bm + row0) * KDIM + kof;
  const size_t boff = (size_t)(bn + row0) * KDIM + kof;
  // wave-uniform LDS bases (lane lands at base + lane*16B = 8 rows per wave)
  short* const la[2] = {&As[0][(wave * 8) * 64], &As[1][(wave * 8) * 64]};
  short* const lb[2] = {&Bs[0][(wave * 8) * 64], &Bs[1][(wave * 8) * 64]};

#define STAGE(buf, k0)                                                              \
  do {                                                                              \
    _Pragma("unroll") for (int p = 0; p < 4; ++p)                                   \
        async_copy16(Xb + aoff + (size_t)p * 64 * KDIM + (k0), la[buf] + p * 4096); \
    _Pragma("unroll") for (int p = 0; p < 2; ++p)                                   \
        async_copy16(Wt + boff + (size_t)p * 64 * KDIM + (k0), lb[buf] + p * 4096); \
  } while (0)

  STAGE(0, 0);
  __syncthreads();  // tile 0 resident

  for (int kt = 0; kt < KDIM / 64; ++kt) {
    const int cur = kt & 1;
    if (kt + 1 < KDIM / 64) {
      if (cur) STAGE(0, (kt + 1) * 64);
      else     STAGE(1, (kt + 1) * 64);
    }
    const short* Ab = As[cur];
    const short* Bb = Bs[cur];
#pragma unroll
    for (int kk = 0; kk < 64; kk += 32) {
      const int sbase = kk >> 3;
      bf16x8 af[4], bfr[4];
#pragma unroll
      for (int i = 0; i < 4; ++i)
        af[i] = *(const bf16x8*)&Ab[(wm + i * 16 + l16) * 64 + (((sbase + quad) ^ lx) << 3)];
#pragma unroll
      for (int j = 0; j < 4; ++j)
        bfr[j] = *(const bf16x8*)&Bb[(wn + j * 16 + l16) * 64 + (((sbase + quad) ^ lx) << 3)];
#pragma unroll
      for (int i = 0; i < 4; ++i)
#pragma unroll
        for (int j = 0; j < 4; ++j)
          acc[i][j] = __builtin_amdgcn_mfma_f32_16x16x32_bf16(af[i], bfr[j], acc[i][j], 0, 0, 0);
    }
    // single barrier per tile: (a) drains this iter's prefetch (had full compute
    // window to land), (b) gates buf[cur] reuse by next iter's STAGE.
    __syncthreads();
  }
#undef STAGE

  // epilogue: C/D layout col=lane&15, row=quad*4+reg
#pragma unroll
  for (int i = 0; i < 4; ++i) {
    const int r0 = bm + wm + i * 16 + quad * 4;
#pragma unroll
    for (int j = 0; j < 4; ++j) {
      const int col = bn + wn + j * 16 + l16;
#pragma unroll
      for (int r = 0; r < 4; ++r)
        Out[(size_t)(r0 + r) * NDIM + col] = acc[i][j][r];
    }
  }
}

// ---------------- fallback (fused, used only if ws too small) ----------------
constexpr int BKP = 72;
__global__ __launch_bounds__(256, 2)
void marlin_int4_gemm(const float* __restrict__ X, const int* __restrict__ Q,
                      const float* __restrict__ S, float* __restrict__ Out) {
  __shared__ short As[128 * BKP];
  __shared__ short Bs[128 * BKP];
  const int bm = blockIdx.x * 128, bn = blockIdx.y * 128;
  const int tid = threadIdx.x, lane = tid & 63, wave = tid >> 6;
  const int wm = (wave & 1) * 64, wn = (wave >> 1) * 64;
  const int quad = lane >> 4, l16 = lane & 15;
  const int nB = tid & 127, krB = (tid >> 7) * 32;
  f32x4 acc[4][4];
#pragma unroll
  for (int i = 0; i < 4; ++i)
#pragma unroll
    for (int j = 0; j < 4; ++j) acc[i][j] = (f32x4){0.f, 0.f, 0.f, 0.f};
  for (int kt = 0; kt < KDIM / 64; ++kt) {
    const int k0 = kt * 64;
    const float s = S[kt * NDIM + bn + nB];
    const float bias = -8.0f * s;
    __syncthreads();
#pragma unroll
    for (int i = 0; i < 8; ++i) {
      const int idx4 = tid + (i << 8);
      const int row = idx4 >> 4, col = (idx4 & 15) << 2;
      const float4 v = *(const float4*)(X + (size_t)(bm + row) * KDIM + k0 + col);
      ushort4 b;
      b.x = f2bf(v.x); b.y = f2bf(v.y); b.z = f2bf(v.z); b.w = f2bf(v.w);
      *(ushort4*)(&As[row * BKP + col]) = b;
    }
    unsigned short wb[32];
#pragma unroll
    for (int j = 0; j < 32; ++j) {
      const int qv = Q[(size_t)(k0 + krB + j) * NDIM + bn + nB];
      wb[j] = f2bf((float)qv * s + bias);
    }
    {
      short* brow = &Bs[nB * BKP + krB];
#pragma unroll
      for (int c = 0; c < 4; ++c) {
        bf16x8 v;
#pragma unroll
        for (int e = 0; e < 8; ++e) v[e] = (short)wb[c * 8 + e];
        *(bf16x8*)(brow + c * 8) = v;
      }
    }
    __syncthreads();
#pragma unroll
    for (int kk = 0; kk < 64; kk += 32) {
      bf16x8 af[4], bfr[4];
#pragma unroll
      for (int i = 0; i < 4; ++i)
        af[i] = *(const bf16x8*)&As[(wm + i * 16 + l16) * BKP + kk + quad * 8];
#pragma unroll
      for (int j = 0; j < 4; ++j)
        bfr[j] = *(const bf16x8*)&Bs[(wn + j * 16 + l16) * BKP + kk + quad * 8];
#pragma unroll
      for (int i = 0; i < 4; ++i)
#pragma unroll
        for (int j = 0; j < 4; ++j)
          acc[i][j] = __builtin_amdgcn_mfma_f32_16x16x32_bf16(af[i], bfr[j], acc[i][j], 0, 0, 0);
    }
  }
#pragma unroll
  for (int i = 0; i < 4; ++i) {
    const int r0 = bm + wm + i * 16 + quad * 4;
#pragma unroll
    for (int j = 0; j < 4; ++j) {
      const int col = bn + wn + j * 16 + l16;
#pragma unroll
      for (int r = 0; r < 4; ++r)
        Out[(size_t)(r0 + r) * NDIM + col] = acc[i][j][r];
    }
  }
}

extern "C" void kernel_launch(void* const* d_in, const int* in_sizes, int n_in,
                              void* d_out, int out_size, void* d_ws, size_t ws_size,
                              hipStream_t stream) {
  const float* X = (const float*)d_in[0];
  const int*   Q = (const int*)d_in[1];
  const float* S = (const float*)d_in[2];
  float* Out = (float*)d_out;

  const size_t xb_elems = (size_t)MDIM * KDIM;
  const size_t wt_elems = (size_t)NDIM * KDIM;
  const size_t need = (xb_elems + wt_elems) * sizeof(short);

  if (ws_size >= need) {
    short* Xb = (short*)d_ws;
    short* Wt = Xb + xb_elems;
    cvt_x_kernel<<<(int)(xb_elems / 8 / 256), 256, 0, stream>>>(X, Xb);
    dequant_w_kernel<<<dim3(KDIM / 64, NDIM / 64), 256, 0, stream>>>(Q, S, Wt);
    gemm_bf16tt<<<dim3(MDIM / 256, NDIM / 128), 512, 0, stream>>>(Xb, Wt, Out);
  } else {
    marlin_int4_gemm<<<dim3(MDIM / 128, NDIM / 128), 256, 0, stream>>>(X, Q, S, Out);
  }
}

// Round 2
// 852.230 us; speedup vs baseline: 1.2192x; 1.2192x over previous
//
#include <hip/hip_runtime.h>

#define MDIM 4096
#define KDIM 4096
#define NDIM 14336

typedef __attribute__((ext_vector_type(8))) short bf16x8;
typedef __attribute__((ext_vector_type(4))) short bf16x4;
typedef __attribute__((ext_vector_type(4))) float f32x4;

// round-to-nearest-even fp32 -> bf16
__device__ __forceinline__ unsigned short f2bf(float f) {
  unsigned u = __float_as_uint(f);
  return (unsigned short)((u + 0x7FFFu + ((u >> 16) & 1u)) >> 16);
}

// async 16B global -> LDS (lane i lands at ldsbase + i*16)
__device__ __forceinline__ void async_copy16(const void* g, void* l) {
  __builtin_amdgcn_global_load_lds((const __attribute__((address_space(1))) unsigned*)g,
                                   (__attribute__((address_space(3))) unsigned*)l, 16, 0, 0);
}

// ---------------- P1: X fp32 -> bf16 ----------------
__global__ __launch_bounds__(256) void cvt_x_kernel(const float* __restrict__ X,
                                                    short* __restrict__ Xb) {
  const int i = blockIdx.x * 256 + threadIdx.x;  // 8 floats per thread
  const float4* p = (const float4*)X + (size_t)i * 2;
  const float4 a = p[0], b = p[1];
  bf16x8 v;
  v[0] = f2bf(a.x); v[1] = f2bf(a.y); v[2] = f2bf(a.z); v[3] = f2bf(a.w);
  v[4] = f2bf(b.x); v[5] = f2bf(b.y); v[6] = f2bf(b.z); v[7] = f2bf(b.w);
  *((bf16x8*)Xb + i) = v;
}

// ---------------- P2 v2: dequant Q[K][N] int32 -> Wt[N][K] bf16 (transposed) ----------------
// 256k x 128n tile per block, 512 threads. Global-access granularity fix:
//   reads : 512 B contiguous per Q row per wave-instruction (32 lanes x 16 B)
//   writes: 128 B full cache line per Wt row per wave-instruction (8 lanes x 16 B),
//           512 B contiguous per row per block; 16 consecutive blocks (grid.x =
//           k-tiles) complete whole 8 KB Wt rows nearly concurrently.
// LDS staging [128 n][264 k-stride] shorts = 66 KiB -> 2 blocks/CU.
constexpr int DQ_STRIDE = 264;  // 256 + 8 pad shorts; 16B-aligned rows
__global__ __launch_bounds__(512) void dequant_w_kernel(const int* __restrict__ Q,
                                                        const float* __restrict__ S,
                                                        short* __restrict__ Wt) {
  __shared__ short Ls[128 * DQ_STRIDE];  // [n][k]
  const int k0 = blockIdx.x * 256;
  const int n0 = blockIdx.y * 128;
  const int t  = threadIdx.x;

  // each chunk: 64 k-rows x 128 n-cols, one 4x4 block per thread
  const int n4  = (t & 31) * 4;   // 0..124
  const int rbi = (t >> 5) * 4;   // 0..60
#pragma unroll
  for (int kc = 0; kc < 4; ++kc) {
    const int g  = (k0 >> 6) + kc;  // GROUP == 64, one scale row per chunk
    const int kb = k0 + kc * 64 + rbi;
    const float4 s4 = *(const float4*)(S + (size_t)g * NDIM + n0 + n4);
    int4 q[4];
#pragma unroll
    for (int i = 0; i < 4; ++i)
      q[i] = *(const int4*)(Q + (size_t)(kb + i) * NDIM + n0 + n4);
    // register transpose: column j -> 4 consecutive k at LDS [n4+j][kc*64+rbi]
    short* lp = &Ls[n4 * DQ_STRIDE + kc * 64 + rbi];
    bf16x4 v;
    v[0] = (short)f2bf((float)(q[0].x - 8) * s4.x);
    v[1] = (short)f2bf((float)(q[1].x - 8) * s4.x);
    v[2] = (short)f2bf((float)(q[2].x - 8) * s4.x);
    v[3] = (short)f2bf((float)(q[3].x - 8) * s4.x);
    *(bf16x4*)(lp + 0 * DQ_STRIDE) = v;
    v[0] = (short)f2bf((float)(q[0].y - 8) * s4.y);
    v[1] = (short)f2bf((float)(q[1].y - 8) * s4.y);
    v[2] = (short)f2bf((float)(q[2].y - 8) * s4.y);
    v[3] = (short)f2bf((float)(q[3].y - 8) * s4.y);
    *(bf16x4*)(lp + 1 * DQ_STRIDE) = v;
    v[0] = (short)f2bf((float)(q[0].z - 8) * s4.z);
    v[1] = (short)f2bf((float)(q[1].z - 8) * s4.z);
    v[2] = (short)f2bf((float)(q[2].z - 8) * s4.z);
    v[3] = (short)f2bf((float)(q[3].z - 8) * s4.z);
    *(bf16x4*)(lp + 2 * DQ_STRIDE) = v;
    v[0] = (short)f2bf((float)(q[0].w - 8) * s4.w);
    v[1] = (short)f2bf((float)(q[1].w - 8) * s4.w);
    v[2] = (short)f2bf((float)(q[2].w - 8) * s4.w);
    v[3] = (short)f2bf((float)(q[3].w - 8) * s4.w);
    *(bf16x4*)(lp + 3 * DQ_STRIDE) = v;
  }
  __syncthreads();

  // write phase: 2 passes x 64 rows; 8 lanes/row x 16 B -> 128 B line per instr
  const int c = (t & 7) * 8;  // 0..56 shorts
#pragma unroll
  for (int p = 0; p < 2; ++p) {
    const int nr = (t >> 3) + p * 64;  // 0..127
    const short* lr = &Ls[nr * DQ_STRIDE + c];
    short* wp = Wt + (size_t)(n0 + nr) * KDIM + k0 + c;
#pragma unroll
    for (int r = 0; r < 4; ++r)
      *(bf16x8*)(wp + r * 64) = *(const bf16x8*)(lr + r * 64);
  }
}

// ---------------- GEMM: Xb[M][K] x Wt[N][K] -> Out[M][N], XOR-swizzled LDS ----------------
// (proven v1 structure: 128x128 tile, 256 thr, 32 KiB LDS, ~3 blocks/CU TLP)
__global__ __launch_bounds__(256, 2)
void gemm_bf16tt(const short* __restrict__ Xb, const short* __restrict__ Wt,
                 float* __restrict__ Out) {
  __shared__ short As[128 * 64];
  __shared__ short Bs[128 * 64];

  const int bm = blockIdx.x * 128;
  const int bn = blockIdx.y * 128;
  const int tid = threadIdx.x, lane = tid & 63, wave = tid >> 6;
  const int wm = (wave & 1) * 64, wn = (wave >> 1) * 64;
  const int quad = lane >> 4, l16 = lane & 15;
  const int lx = l16 & 7;  // row&7 for fragment rows

  f32x4 acc[4][4];
#pragma unroll
  for (int i = 0; i < 4; ++i)
#pragma unroll
    for (int j = 0; j < 4; ++j) acc[i][j] = (f32x4){0.f, 0.f, 0.f, 0.f};

  // staging: chunk (p*256+tid) -> LDS row p*32 + (tid>>3), slot tid&7
  // global k-chunk is XOR-swizzled: kof = ((tid&7) ^ (row&7)) * 8
  const int row0 = tid >> 3;
  const int kof  = (((tid & 7) ^ (row0 & 7))) * 8;
  const size_t aoff = (size_t)(bm + row0) * KDIM + kof;
  const size_t boff = (size_t)(bn + row0) * KDIM + kof;
  short* const la = &As[(wave * 64) * 8];  // wave-uniform base
  short* const lb = &Bs[(wave * 64) * 8];

  for (int kt = 0; kt < KDIM / 64; ++kt) {
    const int k0 = kt * 64;
    __syncthreads();  // previous tile's compute done
#pragma unroll
    for (int p = 0; p < 4; ++p) {
      async_copy16(Xb + aoff + (size_t)p * 32 * KDIM + k0, la + p * 2048);
      async_copy16(Wt + boff + (size_t)p * 32 * KDIM + k0, lb + p * 2048);
    }
    __syncthreads();  // staging complete

#pragma unroll
    for (int kk = 0; kk < 64; kk += 32) {
      const int sbase = kk >> 3;
      bf16x8 af[4], bfr[4];
#pragma unroll
      for (int i = 0; i < 4; ++i)
        af[i] = *(const bf16x8*)&As[(wm + i * 16 + l16) * 64 + (((sbase + quad) ^ lx) << 3)];
#pragma unroll
      for (int j = 0; j < 4; ++j)
        bfr[j] = *(const bf16x8*)&Bs[(wn + j * 16 + l16) * 64 + (((sbase + quad) ^ lx) << 3)];
#pragma unroll
      for (int i = 0; i < 4; ++i)
#pragma unroll
        for (int j = 0; j < 4; ++j)
          acc[i][j] = __builtin_amdgcn_mfma_f32_16x16x32_bf16(af[i], bfr[j], acc[i][j], 0, 0, 0);
    }
  }

  // epilogue: C/D layout col=lane&15, row=quad*4+reg
#pragma unroll
  for (int i = 0; i < 4; ++i) {
    const int r0 = bm + wm + i * 16 + quad * 4;
#pragma unroll
    for (int j = 0; j < 4; ++j) {
      const int col = bn + wn + j * 16 + l16;
#pragma unroll
      for (int r = 0; r < 4; ++r)
        Out[(size_t)(r0 + r) * NDIM + col] = acc[i][j][r];
    }
  }
}

// ---------------- fallback (fused, used only if ws too small) ----------------
constexpr int BKP = 72;
__global__ __launch_bounds__(256, 2)
void marlin_int4_gemm(const float* __restrict__ X, const int* __restrict__ Q,
                      const float* __restrict__ S, float* __restrict__ Out) {
  __shared__ short As[128 * BKP];
  __shared__ short Bs[128 * BKP];
  const int bm = blockIdx.x * 128, bn = blockIdx.y * 128;
  const int tid = threadIdx.x, lane = tid & 63, wave = tid >> 6;
  const int wm = (wave & 1) * 64, wn = (wave >> 1) * 64;
  const int quad = lane >> 4, l16 = lane & 15;
  const int nB = tid & 127, krB = (tid >> 7) * 32;
  f32x4 acc[4][4];
#pragma unroll
  for (int i = 0; i < 4; ++i)
#pragma unroll
    for (int j = 0; j < 4; ++j) acc[i][j] = (f32x4){0.f, 0.f, 0.f, 0.f};
  for (int kt = 0; kt < KDIM / 64; ++kt) {
    const int k0 = kt * 64;
    const float s = S[kt * NDIM + bn + nB];
    const float bias = -8.0f * s;
    __syncthreads();
#pragma unroll
    for (int i = 0; i < 8; ++i) {
      const int idx4 = tid + (i << 8);
      const int row = idx4 >> 4, col = (idx4 & 15) << 2;
      const float4 v = *(const float4*)(X + (size_t)(bm + row) * KDIM + k0 + col);
      ushort4 b;
      b.x = f2bf(v.x); b.y = f2bf(v.y); b.z = f2bf(v.z); b.w = f2bf(v.w);
      *(ushort4*)(&As[row * BKP + col]) = b;
    }
    unsigned short wb[32];
#pragma unroll
    for (int j = 0; j < 32; ++j) {
      const int qv = Q[(size_t)(k0 + krB + j) * NDIM + bn + nB];
      wb[j] = f2bf((float)qv * s + bias);
    }
    {
      short* brow = &Bs[nB * BKP + krB];
#pragma unroll
      for (int c = 0; c < 4; ++c) {
        bf16x8 v;
#pragma unroll
        for (int e = 0; e < 8; ++e) v[e] = (short)wb[c * 8 + e];
        *(bf16x8*)(brow + c * 8) = v;
      }
    }
    __syncthreads();
#pragma unroll
    for (int kk = 0; kk < 64; kk += 32) {
      bf16x8 af[4], bfr[4];
#pragma unroll
      for (int i = 0; i < 4; ++i)
        af[i] = *(const bf16x8*)&As[(wm + i * 16 + l16) * BKP + kk + quad * 8];
#pragma unroll
      for (int j = 0; j < 4; ++j)
        bfr[j] = *(const bf16x8*)&Bs[(wn + j * 16 + l16) * BKP + kk + quad * 8];
#pragma unroll
      for (int i = 0; i < 4; ++i)
#pragma unroll
        for (int j = 0; j < 4; ++j)
          acc[i][j] = __builtin_amdgcn_mfma_f32_16x16x32_bf16(af[i], bfr[j], acc[i][j], 0, 0, 0);
    }
  }
#pragma unroll
  for (int i = 0; i < 4; ++i) {
    const int r0 = bm + wm + i * 16 + quad * 4;
#pragma unroll
    for (int j = 0; j < 4; ++j) {
      const int col = bn + wn + j * 16 + l16;
#pragma unroll
      for (int r = 0; r < 4; ++r)
        Out[(size_t)(r0 + r) * NDIM + col] = acc[i][j][r];
    }
  }
}

extern "C" void kernel_launch(void* const* d_in, const int* in_sizes, int n_in,
                              void* d_out, int out_size, void* d_ws, size_t ws_size,
                              hipStream_t stream) {
  const float* X = (const float*)d_in[0];
  const int*   Q = (const int*)d_in[1];
  const float* S = (const float*)d_in[2];
  float* Out = (float*)d_out;

  const size_t xb_elems = (size_t)MDIM * KDIM;
  const size_t wt_elems = (size_t)NDIM * KDIM;
  const size_t need = (xb_elems + wt_elems) * sizeof(short);

  if (ws_size >= need) {
    short* Xb = (short*)d_ws;
    short* Wt = Xb + xb_elems;
    cvt_x_kernel<<<(int)(xb_elems / 8 / 256), 256, 0, stream>>>(X, Xb);
    dequant_w_kernel<<<dim3(KDIM / 256, NDIM / 128), 512, 0, stream>>>(Q, S, Wt);
    gemm_bf16tt<<<dim3(MDIM / 128, NDIM / 128), 256, 0, stream>>>(Xb, Wt, Out);
  } else {
    marlin_int4_gemm<<<dim3(MDIM / 128, NDIM / 128), 256, 0, stream>>>(X, Q, S, Out);
  }
}